// Round 3
// baseline (521.124 us; speedup 1.0000x reference)
//
#include <hip/hip_runtime.h>
#include <hip/hip_bf16.h>

// ---------------------------------------------------------------------------
// Fused attention block, bf16-MFMA pipeline:
//   1) cast x -> bf16                      (xb)
//   2) transpose-cast Wqkv, Wout -> bf16   (wqkvT, woutT)  [N,K] layout
//   3) GEMM qkv = xb @ WqkvT^T + bqkv      -> q(plain) k(swizzled) v(plain), bf16
//   4) flash attention (mask fp32, online softmax) -> ctx bf16
//   5) GEMM out = ctx @ WoutT^T + bout     -> d_out fp32
// B=2 S=2048 D=1024 H=16 HD=64
// ws layout (40 MB): [xb|ctx 8MB][wqkvT 6MB][woutT 2MB][q 8MB][k 8MB][v 8MB]
// ---------------------------------------------------------------------------

typedef __attribute__((ext_vector_type(8))) __bf16 bf16x8;
typedef __attribute__((ext_vector_type(4))) float  f32x4;

#define LDS_AS __attribute__((address_space(3)))
#define GLB_AS __attribute__((address_space(1)))

__device__ __forceinline__ void gl_lds16(const void* g, void* l) {
  // async global->LDS, 16B per lane; LDS dest = wave-uniform base + lane*16
  __builtin_amdgcn_global_load_lds((GLB_AS void*)g, (LDS_AS void*)l, 16, 0, 0);
}

__device__ __forceinline__ f32x4 mfma16(bf16x8 a, bf16x8 b, f32x4 c) {
  return __builtin_amdgcn_mfma_f32_16x16x32_bf16(a, b, c, 0, 0, 0);
}

// --------------------------- elementwise cast ------------------------------
__global__ __launch_bounds__(256) void cast_bf16_kernel(const float* __restrict__ in,
                                                        __bf16* __restrict__ out) {
  size_t i = (size_t)blockIdx.x * 256 + threadIdx.x;   // one per 8 elems
  const float4* p = (const float4*)in;
  float4 a = p[i * 2], b = p[i * 2 + 1];
  bf16x8 o;
  o[0] = (__bf16)a.x; o[1] = (__bf16)a.y; o[2] = (__bf16)a.z; o[3] = (__bf16)a.w;
  o[4] = (__bf16)b.x; o[5] = (__bf16)b.y; o[6] = (__bf16)b.z; o[7] = (__bf16)b.w;
  *(bf16x8*)(out + i * 8) = o;
}

// ------------------------ transpose-cast (R,C)->(C,R) ----------------------
__global__ __launch_bounds__(256) void tcast_kernel(const float* __restrict__ in,
                                                    __bf16* __restrict__ out,
                                                    int R, int C) {
  __shared__ float t[32][33];
  int c0 = blockIdx.x * 32, r0 = blockIdx.y * 32;
  int tx = threadIdx.x & 31, ty = threadIdx.x >> 5;   // ty 0..7
#pragma unroll
  for (int i = 0; i < 32; i += 8)
    t[ty + i][tx] = in[(size_t)(r0 + ty + i) * C + c0 + tx];
  __syncthreads();
#pragma unroll
  for (int i = 0; i < 32; i += 8)
    out[(size_t)(c0 + ty + i) * R + r0 + tx] = (__bf16)t[tx][ty + i];
}

// ------------------------------- GEMM --------------------------------------
// C[M,N] = A[M,K] * Bt[N,K]^T + bias.  128x128 tile, BK=64, 4 waves (2x2 of 64x64).
// EPI=0: scatter to q/k/v (bf16, k swizzled).  EPI=1: fp32 out.
template <int EPI>
__global__ __launch_bounds__(256, 2) void gemm_bt_kernel(
    const __bf16* __restrict__ A, const __bf16* __restrict__ Bt,
    const float* __restrict__ bias, float* __restrict__ outF,
    __bf16* __restrict__ q, __bf16* __restrict__ k, __bf16* __restrict__ v,
    int N, int K) {
  __shared__ __bf16 As[128 * 64];
  __shared__ __bf16 Bs[128 * 64];
  const int tid = threadIdx.x;
  const int l = tid & 63, w = tid >> 6;
  const int li = l & 15, g = l >> 4;
  const int wr = w >> 1, wc = w & 1;
  const int bm = blockIdx.y * 128, bn = blockIdx.x * 128;

  f32x4 acc[4][4];
  const f32x4 z4 = {0.f, 0.f, 0.f, 0.f};
#pragma unroll
  for (int i = 0; i < 4; ++i)
#pragma unroll
    for (int j = 0; j < 4; ++j) acc[i][j] = z4;

  for (int k0 = 0; k0 < K; k0 += 64) {
    __syncthreads();  // previous readers done
    // stage 16KB each of A,B; LDS linear, global source inverse-XOR-swizzled
#pragma unroll
    for (int i = 0; i < 4; ++i) {
      int cb = (i * 4 + w) * 64 + l;        // 16B-chunk id 0..1023
      int r = cb >> 3, c = cb & 7;
      int sc = c ^ (r & 7);
      gl_lds16(A  + (size_t)(bm + r) * K + k0 + sc * 8, (char*)As + (i * 4 + w) * 1024);
      gl_lds16(Bt + (size_t)(bn + r) * K + k0 + sc * 8, (char*)Bs + (i * 4 + w) * 1024);
    }
    __syncthreads();  // staged data visible (barrier drains vmcnt)
#pragma unroll
    for (int ks = 0; ks < 2; ++ks) {
      bf16x8 af[4], bfv[4];
#pragma unroll
      for (int i = 0; i < 4; ++i) {
        int ra = wr * 64 + i * 16 + li;
        af[i]  = *(const bf16x8*)((const char*)As + ra * 128 + (((ks * 4 + g) ^ (ra & 7)) * 16));
        int rb = wc * 64 + i * 16 + li;
        bfv[i] = *(const bf16x8*)((const char*)Bs + rb * 128 + (((ks * 4 + g) ^ (rb & 7)) * 16));
      }
#pragma unroll
      for (int i = 0; i < 4; ++i)
#pragma unroll
        for (int j = 0; j < 4; ++j)
          acc[i][j] = mfma16(af[i], bfv[j], acc[i][j]);
    }
  }

  // epilogue: C row m = bm+wr*64+i*16+g*4+jj ; col n = bn+wc*64+j*16+li
#pragma unroll
  for (int j = 0; j < 4; ++j) {
    int n = bn + wc * 64 + j * 16 + li;
    float bj = bias[n];
#pragma unroll
    for (int i = 0; i < 4; ++i) {
      int mb = bm + wr * 64 + i * 16 + g * 4;
#pragma unroll
      for (int jj = 0; jj < 4; ++jj) {
        float val = acc[i][j][jj] + bj;
        int m = mb + jj;
        if (EPI == 0) {
          int which = n >> 10, col = n & 1023, hh = col >> 6, hd = col & 63;
          int bb = m >> 11, s = m & 2047;
          size_t base = ((size_t)(bb * 16 + hh) * 2048 + s) * 64;
          __bf16 hv = (__bf16)val;
          if (which == 0)      q[base + hd] = hv;                                   // plain
          else if (which == 1) k[base + ((hd & 7) | (((hd >> 3) ^ (s & 7)) << 3))] = hv; // XOR-swz
          else                 v[base + hd] = hv;                                   // plain
        } else {
          outF[(size_t)m * N + n] = val;
        }
      }
    }
  }
}

// ---------------------------- flash attention ------------------------------
// grid (h=16, qt=32); 256 thr = 4 waves: wave w -> batch w>>1, q rows qt*64+(w&1)*32..+32
// Mask tile (q rows x 64 keys) shared by the two batches -> mask read ~once from HBM.
// Swizzle helpers (both-sides-or-neither, rule 21):
//   K  : slot = chunk ^ (key & 7)            (baked into global by gemm<0>)
//   Vt : slot = (key>>3) ^ ((hd ^ (hd>>3))&7)  -> write 2-way, read 2-way (free)
//   Ps : slot = chunk ^ ((pr ^ (pr>>2))&7)     -> write 2-way, read 2-way (free)
__global__ __launch_bounds__(256, 2) void attn_kernel(
    const __bf16* __restrict__ qg, const __bf16* __restrict__ kg,
    const __bf16* __restrict__ vg, const float* __restrict__ mask,
    __bf16* __restrict__ ctx) {
  __shared__ __bf16 Ks[2 * 64 * 64];   // [b][key][hd-slot swizzled] (global pre-swizzled)
  __shared__ __bf16 Vt[2 * 64 * 64];   // [b][hd][key-slot swizzled]
  __shared__ __bf16 Ps[4 * 32 * 64];   // per-wave P, swizzled
  const int tid = threadIdx.x;
  const int l = tid & 63, w = tid >> 6;
  const int li = l & 15, g = l >> 4;
  const int h = blockIdx.x, qt = blockIdx.y;
  const int b = w >> 1;
  const int qbase = qt * 64 + (w & 1) * 32;
  // scalar (no runtime-indexed array -> no scratch, rule 20)
  const size_t kvb_b = ((size_t)(b * 16 + h)) * 2048 * 64;

  // Q fragments held in registers (A-operand of QK^T)
  bf16x8 aq[2][2];
#pragma unroll
  for (int fr = 0; fr < 2; ++fr)
#pragma unroll
    for (int ks = 0; ks < 2; ++ks)
      aq[fr][ks] = *(const bf16x8*)(qg + kvb_b + (size_t)(qbase + fr * 16 + li) * 64 + ks * 32 + g * 8);

  float mrun[2][4], lrun[2][4];
  f32x4 acco[2][4];
  const f32x4 z4 = {0.f, 0.f, 0.f, 0.f};
#pragma unroll
  for (int fr = 0; fr < 2; ++fr)
#pragma unroll
    for (int jj = 0; jj < 4; ++jj) { mrun[fr][jj] = -1e30f; lrun[fr][jj] = 0.f; }
#pragma unroll
  for (int fr = 0; fr < 2; ++fr)
#pragma unroll
    for (int hf = 0; hf < 4; ++hf) acco[fr][hf] = z4;

  const size_t maskh = (size_t)h * 2048 * 2048;

  for (int kt = 0; kt < 32; ++kt) {
    // stage K (both batches, 16KB linear; swizzle already baked into global)
#pragma unroll
    for (int i = 0; i < 4; ++i) {
      int cb = (i * 4 + w) * 64 + l;
      int bb = cb >> 9;
      gl_lds16(kg + ((size_t)(bb * 16 + h)) * 131072 + (size_t)kt * 4096 + (size_t)(cb & 511) * 8,
               (char*)Ks + (i * 4 + w) * 1024);
    }
    // stage V transposed: Vt[b][hd][key-slot]; slot = (key>>3) ^ ((hd^(hd>>3))&7)
#pragma unroll
    for (int t = 0; t < 4; ++t) {
      int ch = t * 256 + tid;
      int bb = ch >> 9, key = (ch >> 3) & 63, hc = ch & 7;
      bf16x8 vv = *(const bf16x8*)(vg + ((size_t)(bb * 16 + h)) * 131072 +
                                   ((size_t)kt * 64 + key) * 64 + hc * 8);
#pragma unroll
      for (int e = 0; e < 8; ++e) {
        int hd = hc * 8 + e;
        int slot = (key >> 3) ^ ((hd ^ (hd >> 3)) & 7);
        Vt[bb * 4096 + hd * 64 + slot * 8 + (key & 7)] = vv[e];
      }
    }
    __syncthreads();

    // ---- QK^T: scores[q][key], 16 MFMAs ----
    f32x4 accs[2][4];
#pragma unroll
    for (int fr = 0; fr < 2; ++fr)
#pragma unroll
      for (int cf = 0; cf < 4; ++cf) accs[fr][cf] = z4;
#pragma unroll
    for (int ks = 0; ks < 2; ++ks) {
      bf16x8 bk[4];
#pragma unroll
      for (int cf = 0; cf < 4; ++cf) {
        int kr = cf * 16 + li;
        int slot = (ks * 4 + g) ^ (kr & 7);
        bk[cf] = *(const bf16x8*)((const char*)Ks + b * 8192 + kr * 128 + slot * 16);
      }
#pragma unroll
      for (int fr = 0; fr < 2; ++fr)
#pragma unroll
        for (int cf = 0; cf < 4; ++cf)
          accs[fr][cf] = mfma16(aq[fr][ks], bk[cf], accs[fr][cf]);
    }
    // ---- scale + mask ----
#pragma unroll
    for (int fr = 0; fr < 2; ++fr)
#pragma unroll
      for (int cf = 0; cf < 4; ++cf)
#pragma unroll
        for (int jj = 0; jj < 4; ++jj) {
          size_t mi = maskh + (size_t)(qbase + fr * 16 + g * 4 + jj) * 2048 + kt * 64 + cf * 16 + li;
          accs[fr][cf][jj] = fmaf(accs[fr][cf][jj], 0.125f, mask[mi]);
        }
    // ---- online softmax (16-lane butterflies; row lives in same-g lanes) ----
#pragma unroll
    for (int fr = 0; fr < 2; ++fr)
#pragma unroll
      for (int jj = 0; jj < 4; ++jj) {
        float tm = fmaxf(fmaxf(accs[fr][0][jj], accs[fr][1][jj]),
                         fmaxf(accs[fr][2][jj], accs[fr][3][jj]));
#pragma unroll
        for (int mk = 1; mk < 16; mk <<= 1) tm = fmaxf(tm, __shfl_xor(tm, mk, 16));
        float mnew = fmaxf(mrun[fr][jj], tm);
        float scl = __expf(mrun[fr][jj] - mnew);
        mrun[fr][jj] = mnew;
        float ssum = 0.f;
#pragma unroll
        for (int cf = 0; cf < 4; ++cf) {
          float p = __expf(accs[fr][cf][jj] - mnew);
          accs[fr][cf][jj] = p;
          ssum += p;
        }
#pragma unroll
        for (int mk = 1; mk < 16; mk <<= 1) ssum += __shfl_xor(ssum, mk, 16);
        lrun[fr][jj] = lrun[fr][jj] * scl + ssum;
#pragma unroll
        for (int hf = 0; hf < 4; ++hf) acco[fr][hf][jj] *= scl;
      }
    // ---- P -> per-wave LDS (bf16); slot = cc ^ ((pr^(pr>>2))&7) ----
#pragma unroll
    for (int fr = 0; fr < 2; ++fr)
#pragma unroll
      for (int cf = 0; cf < 4; ++cf)
#pragma unroll
        for (int jj = 0; jj < 4; ++jj) {
          int pr = fr * 16 + g * 4 + jj;
          int cc = cf * 2 + (li >> 3);
          int slot = cc ^ ((pr ^ (pr >> 2)) & 7);
          Ps[w * 2048 + pr * 64 + slot * 8 + (li & 7)] = (__bf16)accs[fr][cf][jj];
        }
    asm volatile("s_waitcnt lgkmcnt(0)" ::: "memory");  // own-wave Ps RAW
    __builtin_amdgcn_sched_barrier(0);                  // rule #18: pin it
    // ---- PV: ctx += P @ V, 16 MFMAs ----
#pragma unroll
    for (int ks = 0; ks < 2; ++ks) {
      bf16x8 ap[2], bv[4];
#pragma unroll
      for (int fr = 0; fr < 2; ++fr) {
        int r = fr * 16 + li;
        int slot = (ks * 4 + g) ^ ((r ^ (r >> 2)) & 7);
        ap[fr] = *(const bf16x8*)((const char*)Ps + w * 4096 + r * 128 + slot * 16);
      }
#pragma unroll
      for (int hf = 0; hf < 4; ++hf) {
        int hd = hf * 16 + li;
        int slot = (ks * 4 + g) ^ ((hd ^ (hd >> 3)) & 7);
        bv[hf] = *(const bf16x8*)((const char*)Vt + b * 8192 + hd * 128 + slot * 16);
      }
#pragma unroll
      for (int fr = 0; fr < 2; ++fr)
#pragma unroll
        for (int hf = 0; hf < 4; ++hf)
          acco[fr][hf] = mfma16(ap[fr], bv[hf], acco[fr][hf]);
    }
    __syncthreads();  // protect K/V LDS before next stage
  }

  // epilogue: ctx[b][s][h*64+hd] bf16
#pragma unroll
  for (int fr = 0; fr < 2; ++fr)
#pragma unroll
    for (int hf = 0; hf < 4; ++hf)
#pragma unroll
      for (int jj = 0; jj < 4; ++jj) {
        int qrow = qbase + fr * 16 + g * 4 + jj;
        float val = acco[fr][hf][jj] / lrun[fr][jj];
        ctx[((size_t)b * 2048 + qrow) * 1024 + h * 64 + hf * 16 + li] = (__bf16)val;
      }
}

// ------------------------------- launcher ----------------------------------
extern "C" void kernel_launch(void* const* d_in, const int* in_sizes, int n_in,
                              void* d_out, int out_size, void* d_ws, size_t ws_size,
                              hipStream_t stream) {
  const float* x    = (const float*)d_in[0];
  const float* mask = (const float*)d_in[1];
  const float* Wqkv = (const float*)d_in[2];
  const float* bqkv = (const float*)d_in[3];
  const float* Wout = (const float*)d_in[4];
  const float* bout = (const float*)d_in[5];
  float* out = (float*)d_out;

  constexpr size_t OFF_XB    = 0;          // 4096x1024 bf16 (8 MB); reused as ctx
  constexpr size_t OFF_WQKVT = 8388608;    // 3072x1024 bf16 (6 MB)
  constexpr size_t OFF_WOUTT = 14680064;   // 1024x1024 bf16 (2 MB)
  constexpr size_t OFF_Q     = 16777216;   // 8 MB
  constexpr size_t OFF_K     = 25165824;   // 8 MB
  constexpr size_t OFF_V     = 33554432;   // 8 MB -> total 40 MB
  if (ws_size < 41943040) return;

  char* ws = (char*)d_ws;
  __bf16* xb     = (__bf16*)(ws + OFF_XB);
  __bf16* wqkvT  = (__bf16*)(ws + OFF_WQKVT);
  __bf16* woutT  = (__bf16*)(ws + OFF_WOUTT);
  __bf16* qg     = (__bf16*)(ws + OFF_Q);
  __bf16* kg     = (__bf16*)(ws + OFF_K);
  __bf16* vg     = (__bf16*)(ws + OFF_V);
  __bf16* ctx    = (__bf16*)(ws + OFF_XB);  // alias: xb dead after gemm<0>

  cast_bf16_kernel<<<2048, 256, 0, stream>>>(x, xb);                       // 4M elems
  tcast_kernel<<<dim3(96, 32), 256, 0, stream>>>(Wqkv, wqkvT, 1024, 3072);
  tcast_kernel<<<dim3(32, 32), 256, 0, stream>>>(Wout, woutT, 1024, 1024);
  gemm_bt_kernel<0><<<dim3(24, 32), 256, 0, stream>>>(xb, wqkvT, bqkv, nullptr,
                                                      qg, kg, vg, 3072, 1024);
  attn_kernel<<<dim3(16, 32), 256, 0, stream>>>(qg, kg, vg, mask, ctx);
  gemm_bt_kernel<1><<<dim3(8, 32), 256, 0, stream>>>(ctx, woutT, bout, out,
                                                     nullptr, nullptr, nullptr, 1024, 1024);
}